// Round 2
// baseline (1012.326 us; speedup 1.0000x reference)
//
#include <hip/hip_runtime.h>

constexpr int kNodes = 1000000;
constexpr int kEdges = 32000000;

// ---------------- Tile-sorted scatter path (arena layout) ----------------
// 256 buckets x 4096 nodes. Record u32 = (node&4095)<<16 | q16,
// q16 = clamp(round((orc_other+1)*32768), 0, 65535)  (error <= 1.5e-5).
// scatter_sort counting-sorts each 4096-edge tile by bucket in LDS, then a
// per-(tile,bucket) global cursor atomicAdd allocates a contiguous slot in
// that bucket's arena region; the flush writes each record to its final
// per-bucket-contiguous position. bucket_accum then streams one dense region
// per bucket (fully coalesced uint4 reads), no table indirection, no pads.
constexpr int NB = 256;
constexpr int BSHIFT = 12;
constexpr int BNODES = 4096;
constexpr int NBUSED = (kNodes + BNODES - 1) / BNODES;   // 245
constexpr int EPT = 4096;                 // edges per tile
constexpr int RECS = EPT * 2;             // records per tile
constexpr int TILES = (kEdges + EPT - 1) / EPT;          // 7813
constexpr int CAP = 288768;               // per-bucket record capacity
                                          // mean 261224, sigma~511 -> 54 sigma
constexpr int SPLIT = 2;                  // halves per bucket in accum

constexpr size_t kArenaBytes = (size_t)NBUSED * CAP * 4; // ~283 MB
constexpr size_t kCurOff    = kArenaBytes;
constexpr size_t kCurBytes  = 1024;                      // 256 u32 cursors
constexpr size_t kAccOff    = kCurOff + kCurBytes;
constexpr size_t kAccBytes  = (size_t)SPLIT * kNodes * 4;  // 8 MB
constexpr size_t kOrcqOff   = kAccOff + kAccBytes;
constexpr size_t kOrcqBytes = (size_t)kNodes * 2;        // 2 MB
constexpr size_t kWsNeeded  = kOrcqOff + kOrcqBytes;     // ~293 MB

__global__ __launch_bounds__(256) void quant_orc(
        const float* __restrict__ orc, unsigned short* __restrict__ orcq,
        unsigned* __restrict__ gcur) {
    if (blockIdx.x == 0 && threadIdx.x < NB) gcur[threadIdx.x] = 0u;
    const int i = (blockIdx.x * 256 + threadIdx.x) * 4;
    if (i >= kNodes) return;
    const float4 v = *reinterpret_cast<const float4*>(orc + i);
    unsigned q0 = __float2uint_rn((v.x + 1.0f) * 32768.0f);
    unsigned q1 = __float2uint_rn((v.y + 1.0f) * 32768.0f);
    unsigned q2 = __float2uint_rn((v.z + 1.0f) * 32768.0f);
    unsigned q3 = __float2uint_rn((v.w + 1.0f) * 32768.0f);
    q0 = q0 > 65535u ? 65535u : q0;
    q1 = q1 > 65535u ? 65535u : q1;
    q2 = q2 > 65535u ? 65535u : q2;
    q3 = q3 > 65535u ? 65535u : q3;
    ushort4 q;
    q.x = (unsigned short)q0; q.y = (unsigned short)q1;
    q.z = (unsigned short)q2; q.w = (unsigned short)q3;
    *reinterpret_cast<ushort4*>(orcq + i) = q;
}

__global__ __launch_bounds__(1024) void scatter_sort(
        const int* __restrict__ ei, const unsigned short* __restrict__ orcq,
        unsigned* __restrict__ arena, unsigned* __restrict__ gcur) {
    __shared__ alignas(16) unsigned reorder[RECS];     // 32 KB
    __shared__ unsigned char bucketOf[RECS];           // 8 KB
    __shared__ unsigned cnt[NB];                       // hist -> cursor
    __shared__ unsigned dstadd[NB];                    // arena dst - local st
    __shared__ unsigned totsh;
    const int tid = threadIdx.x;
    const int t = blockIdx.x;
    const int e0 = t * EPT;
    const int ne = min(EPT, kEdges - e0);   // 4096; last tile 2048
    const int k4 = tid * 4;

    if (tid < NB) cnt[tid] = 0u;
    __syncthreads();

    // phase 1: edges -> registers, histogram, EARLY-ISSUED orcq gathers
    int4 s4, d4;
    s4.x = s4.y = s4.z = s4.w = 0; d4 = s4;
    unsigned pq0 = 0, pq1 = 0, pq2 = 0, pq3 = 0;  // (q_for_d<<16)|q_for_s
    const bool act = k4 < ne;
    if (act) {
        s4 = *reinterpret_cast<const int4*>(ei + e0 + k4);
        d4 = *reinterpret_cast<const int4*>(ei + kEdges + e0 + k4);
        const unsigned a0 = orcq[d4.x], a1 = orcq[d4.y],
                       a2 = orcq[d4.z], a3 = orcq[d4.w];   // q(orc[d]) -> s-rec
        const unsigned b0 = orcq[s4.x], b1 = orcq[s4.y],
                       b2 = orcq[s4.z], b3 = orcq[s4.w];   // q(orc[s]) -> d-rec
        atomicAdd(&cnt[(unsigned)s4.x >> BSHIFT], 1u);
        atomicAdd(&cnt[(unsigned)s4.y >> BSHIFT], 1u);
        atomicAdd(&cnt[(unsigned)s4.z >> BSHIFT], 1u);
        atomicAdd(&cnt[(unsigned)s4.w >> BSHIFT], 1u);
        atomicAdd(&cnt[(unsigned)d4.x >> BSHIFT], 1u);
        atomicAdd(&cnt[(unsigned)d4.y >> BSHIFT], 1u);
        atomicAdd(&cnt[(unsigned)d4.z >> BSHIFT], 1u);
        atomicAdd(&cnt[(unsigned)d4.w >> BSHIFT], 1u);
        pq0 = a0 | (b0 << 16);
        pq1 = a1 | (b1 << 16);
        pq2 = a2 | (b2 << 16);
        pq3 = a3 | (b3 << 16);
    }
    __syncthreads();

    // phase 2a: wave-0 shuffle scan of raw counts (no padding) + issue the
    // per-bucket arena cursor atomics (returns consumed AFTER phase 3, so
    // the global-atomic round trip hides under the rank loop).
    unsigned st0 = 0, st1 = 0, st2 = 0, st3 = 0;
    unsigned g0 = 0, g1 = 0, g2 = 0, g3 = 0;
    if (tid < 64) {
        const unsigned c0 = cnt[4 * tid + 0], c1 = cnt[4 * tid + 1];
        const unsigned c2 = cnt[4 * tid + 2], c3 = cnt[4 * tid + 3];
        const unsigned loc = c0 + c1 + c2 + c3;
        unsigned inc = loc;
        #pragma unroll
        for (int d = 1; d < 64; d <<= 1) {
            const unsigned v = (unsigned)__shfl_up((int)inc, d, 64);
            if (tid >= d) inc += v;
        }
        st0 = inc - loc; st1 = st0 + c0; st2 = st1 + c1; st3 = st2 + c2;
        cnt[4 * tid + 0] = st0;
        cnt[4 * tid + 1] = st1;
        cnt[4 * tid + 2] = st2;
        cnt[4 * tid + 3] = st3;
        g0 = atomicAdd(&gcur[4 * tid + 0], c0);
        g1 = atomicAdd(&gcur[4 * tid + 1], c1);
        g2 = atomicAdd(&gcur[4 * tid + 2], c2);
        g3 = atomicAdd(&gcur[4 * tid + 3], c3);
        if (tid == 63) totsh = inc;
    }
    __syncthreads();

    // phase 3: rank + scatter records into reorder buffer (from registers)
    if (act) {
        #define RANK1(S, D, PQ) { \
            const unsigned bs_ = (unsigned)(S) >> BSHIFT; \
            const unsigned rs_ = atomicAdd(&cnt[bs_], 1u); \
            reorder[rs_] = (((unsigned)(S) & (BNODES - 1)) << 16) | ((PQ) & 0xFFFFu); \
            bucketOf[rs_] = (unsigned char)bs_; \
            const unsigned bd_ = (unsigned)(D) >> BSHIFT; \
            const unsigned rd_ = atomicAdd(&cnt[bd_], 1u); \
            reorder[rd_] = (((unsigned)(D) & (BNODES - 1)) << 16) | ((PQ) >> 16); \
            bucketOf[rd_] = (unsigned char)bd_; }
        RANK1(s4.x, d4.x, pq0)
        RANK1(s4.y, d4.y, pq1)
        RANK1(s4.z, d4.z, pq2)
        RANK1(s4.w, d4.w, pq3)
        #undef RANK1
    }
    __syncthreads();

    // phase 2b: dst base per bucket (u32 wrap-around arithmetic is fine:
    // final index = b*CAP + gofs + (k - st) mod 2^32, always in range)
    if (tid < 64) {
        dstadd[4 * tid + 0] = (unsigned)(4 * tid + 0) * CAP + g0 - st0;
        dstadd[4 * tid + 1] = (unsigned)(4 * tid + 1) * CAP + g1 - st1;
        dstadd[4 * tid + 2] = (unsigned)(4 * tid + 2) * CAP + g2 - st2;
        dstadd[4 * tid + 3] = (unsigned)(4 * tid + 3) * CAP + g3 - st3;
    }
    __syncthreads();

    // phase 4: flush to per-bucket-contiguous arena positions. Consecutive k
    // are mostly same-bucket runs (~32 records), so stores are near-contiguous.
    const unsigned total = totsh;
    for (unsigned k = (unsigned)tid; k < total; k += 1024) {
        const unsigned r = reorder[k];
        const unsigned bb = bucketOf[k];
        arena[dstadd[bb] + k] = r;
    }
}

__global__ __launch_bounds__(1024) void bucket_accum(
        const unsigned* __restrict__ arena, const unsigned* __restrict__ gcur,
        unsigned* __restrict__ acc) {
    __shared__ unsigned lacc[BNODES];             // 16 KB
    const int tid = threadIdx.x;
    const int b = blockIdx.x >> 1;
    const int half = blockIdx.x & 1;
    for (int k = tid; k < BNODES; k += 1024) lacc[k] = 0u;
    __syncthreads();
    const unsigned n = gcur[b];
    const unsigned n4 = n >> 2;
    const unsigned h0 = half ? (n4 >> 1) : 0u;
    const unsigned h1 = half ? n4 : (n4 >> 1);
    const uint4* __restrict__ p =
        reinterpret_cast<const uint4*>(arena + (size_t)b * CAP);
    for (unsigned i = h0 + tid; i < h1; i += 1024) {
        const uint4 v = p[i];
        // deg in bits [24,32), sum(q16) in [0,24)
        atomicAdd(&lacc[v.x >> 16], (v.x & 0xFFFFu) | 0x1000000u);
        atomicAdd(&lacc[v.y >> 16], (v.y & 0xFFFFu) | 0x1000000u);
        atomicAdd(&lacc[v.z >> 16], (v.z & 0xFFFFu) | 0x1000000u);
        atomicAdd(&lacc[v.w >> 16], (v.w & 0xFFFFu) | 0x1000000u);
    }
    if (half) {   // tail records (n not multiple of 4)
        for (unsigned k = (n4 << 2) + tid; k < n; k += 1024) {
            const unsigned v = arena[(size_t)b * CAP + k];
            atomicAdd(&lacc[v >> 16], (v & 0xFFFFu) | 0x1000000u);
        }
    }
    __syncthreads();
    const int base = b << BSHIFT;
    unsigned* __restrict__ dst = acc + (size_t)half * kNodes;
    for (int k = tid; k < BNODES; k += 1024) {
        const int nn = base + k;
        if (nn < kNodes) dst[nn] = lacc[k];
    }
}

// ---------------- Fallback (atomic) path ----------------
constexpr float kScale = 1048576.0f;           // 2^20
constexpr float kInvScale = 1.0f / 1048576.0f;
constexpr long long kBias = 1ll << 36;

__global__ __launch_bounds__(256) void zero_acc(unsigned long long* __restrict__ acc) {
    int i = blockIdx.x * 256 + threadIdx.x;
    if (i < kNodes) acc[i] = 0ull;
}

__global__ __launch_bounds__(256) void edge_kernel(
        const int* __restrict__ ei,
        const float* __restrict__ orc,
        unsigned long long* __restrict__ acc) {
    int t = blockIdx.x * 256 + threadIdx.x;
    int e0 = t * 4;
    if (e0 >= kEdges) return;
    const int4 s4 = *reinterpret_cast<const int4*>(ei + e0);
    const int4 d4 = *reinterpret_cast<const int4*>(ei + kEdges + e0);
    const int ss[4] = {s4.x, s4.y, s4.z, s4.w};
    const int dd[4] = {d4.x, d4.y, d4.z, d4.w};
    #pragma unroll
    for (int k = 0; k < 4; ++k) {
        const float os = orc[ss[k]];
        const float od = orc[dd[k]];
        const unsigned long long ps =
            (1ull << 48) + (unsigned long long)(kBias + (long long)__float2ll_rn(od * kScale));
        const unsigned long long pd =
            (1ull << 48) + (unsigned long long)(kBias + (long long)__float2ll_rn(os * kScale));
        atomicAdd(&acc[ss[k]], ps);
        atomicAdd(&acc[dd[k]], pd);
    }
}

// ---------------- Node phase ----------------
// MODE 0: deg<<48 | biased 2^20 fixed sum (u64).
// MODE 3: two u32 partials, each deg<<24 | sum(q16).
template <int MODE>
__global__ __launch_bounds__(256) void node_kernel(
        const float* __restrict__ orc,
        const unsigned long long* __restrict__ acc64,
        const unsigned* __restrict__ acc32,
        const float* __restrict__ W1, const float* __restrict__ b1,
        const float* __restrict__ W2, const float* __restrict__ b2,
        const float* __restrict__ gamma, const float* __restrict__ beta,
        float* __restrict__ out) {
    const int i = blockIdx.x * 256 + threadIdx.x;
    if (i >= kNodes) return;

    const float x0 = orc[i];
    float nb;
    if (MODE == 0) {
        const unsigned long long p = acc64[i];
        const unsigned deg = (unsigned)(p >> 48);
        const long long sf = (long long)(p & ((1ull << 48) - 1)) - (long long)deg * kBias;
        const float s = (float)sf * kInvScale;
        nb = (deg > 0) ? s / (float)deg : 0.0f;
    } else {
        const unsigned p0 = acc32[i];
        const unsigned p1 = acc32[kNodes + i];
        const unsigned deg = (p0 >> 24) + (p1 >> 24);
        const unsigned sumq = (p0 & 0xFFFFFFu) + (p1 & 0xFFFFFFu);
        nb = (deg > 0)
            ? ((float)sumq * (1.0f / 32768.0f) / (float)deg - 1.0f) : 0.0f;
    }

    constexpr float kPi = 3.14159265358979323846f;
    float Phi[16];
    const float n0 = __saturatef((x0 + 1.0f) * 0.5f);
    const float n1 = __saturatef((nb + 1.0f) * 0.5f);
    #pragma unroll
    for (int k = 0; k < 4; ++k) {
        const float a0 = n0 * (float)(k + 1) * kPi;
        const float a1 = n1 * (float)(k + 1) * kPi;
        Phi[2 * k]     = __sinf(a0);
        Phi[2 * k + 1] = __cosf(a0);
        Phi[8 + 2 * k]     = __sinf(a1);
        Phi[8 + 2 * k + 1] = __cosf(a1);
    }

    float y[16];
    #pragma unroll
    for (int d = 0; d < 16; ++d) y[d] = b2[d];
    #pragma unroll
    for (int j = 0; j < 32; ++j) {
        float a = b1[j];
        #pragma unroll
        for (int d = 0; d < 16; ++d) a = fmaf(Phi[d], W1[j * 16 + d], a);
        a = fmaxf(a, 0.0f);
        #pragma unroll
        for (int d = 0; d < 16; ++d) y[d] = fmaf(a, W2[d * 32 + j], y[d]);
    }

    float mu = 0.0f;
    #pragma unroll
    for (int d = 0; d < 16; ++d) mu += y[d];
    mu *= (1.0f / 16.0f);
    float var = 0.0f;
    #pragma unroll
    for (int d = 0; d < 16; ++d) { const float t = y[d] - mu; var = fmaf(t, t, var); }
    var *= (1.0f / 16.0f);
    const float inv = rsqrtf(var + 1e-5f);

    float4* o4 = reinterpret_cast<float4*>(out + (size_t)i * 16);
    #pragma unroll
    for (int q = 0; q < 4; ++q) {
        float4 o;
        o.x = (y[4 * q + 0] - mu) * inv * gamma[4 * q + 0] + beta[4 * q + 0] + Phi[4 * q + 0];
        o.y = (y[4 * q + 1] - mu) * inv * gamma[4 * q + 1] + beta[4 * q + 1] + Phi[4 * q + 1];
        o.z = (y[4 * q + 2] - mu) * inv * gamma[4 * q + 2] + beta[4 * q + 2] + Phi[4 * q + 2];
        o.w = (y[4 * q + 3] - mu) * inv * gamma[4 * q + 3] + beta[4 * q + 3] + Phi[4 * q + 3];
        o4[q] = o;
    }
}

extern "C" void kernel_launch(void* const* d_in, const int* in_sizes, int n_in,
                              void* d_out, int out_size, void* d_ws, size_t ws_size,
                              hipStream_t stream) {
    const float* orc   = (const float*)d_in[0];
    const int*   ei    = (const int*)d_in[1];
    const float* W1    = (const float*)d_in[2];
    const float* b1    = (const float*)d_in[3];
    const float* W2    = (const float*)d_in[4];
    const float* b2    = (const float*)d_in[5];
    const float* gamma = (const float*)d_in[6];
    const float* beta  = (const float*)d_in[7];
    float* out = (float*)d_out;
    char* ws = (char*)d_ws;

    if (ws_size >= kWsNeeded) {
        unsigned* arena = (unsigned*)ws;
        unsigned* gcur = (unsigned*)(ws + kCurOff);
        unsigned* acc = (unsigned*)(ws + kAccOff);
        unsigned short* orcq = (unsigned short*)(ws + kOrcqOff);
        quant_orc<<<(kNodes / 4 + 255) / 256, 256, 0, stream>>>(orc, orcq, gcur);
        scatter_sort<<<TILES, 1024, 0, stream>>>(ei, orcq, arena, gcur);
        bucket_accum<<<NBUSED * SPLIT, 1024, 0, stream>>>(arena, gcur, acc);
        node_kernel<3><<<(kNodes + 255) / 256, 256, 0, stream>>>(
            orc, nullptr, acc, W1, b1, W2, b2, gamma, beta, out);
    } else {
        unsigned long long* acc = (unsigned long long*)ws;  // 8 MB
        zero_acc<<<(kNodes + 255) / 256, 256, 0, stream>>>(acc);
        edge_kernel<<<(kEdges / 4 + 255) / 256, 256, 0, stream>>>(ei, orc, acc);
        node_kernel<0><<<(kNodes + 255) / 256, 256, 0, stream>>>(
            orc, acc, nullptr, W1, b1, W2, b2, gamma, beta, out);
    }
}

// Round 3
// 902.896 us; speedup vs baseline: 1.1212x; 1.1212x over previous
//
#include <hip/hip_runtime.h>

constexpr int kNodes = 1000000;
constexpr int kEdges = 32000000;

// ---------------- Tile-sorted scatter path ----------------
// 256 buckets x 4096 nodes. Record u32 = (node&4095)<<16 | q16,
// q16 = clamp(round((orc_other+1)*32768), 0, 65535)  (error <= 1.5e-5).
// scatter_sort counting-sorts each 4096-edge tile by bucket in LDS and
// flushes the tile's 8192 records with full-line int4 stores (NO padding,
// no sentinels: the consumer reads u32-granular). Per-tile segment table is
// [tile][bucket] (contiguous 514 B per tile -> coalesced writes).
// bucket_accum assigns one WAVE per (bucket,tile) segment: 64 lanes read
// consecutive u32 records (1 wave-load covers the ~132 B segment) and
// accumulate deg<<24 | sum(q16) into a 4096-entry LDS table.
constexpr int NB = 256;
constexpr int BSHIFT = 12;
constexpr int BNODES = 4096;
constexpr int NBUSED = (kNodes + BNODES - 1) / BNODES;   // 245
constexpr int EPT = 4096;                 // edges per tile
constexpr int RECS = EPT * 2;             // records per tile (8192)
constexpr int TILES = (kEdges + EPT - 1) / EPT;          // 7813
constexpr int TROW = NB + 1;              // tbl row: 256 starts + total
constexpr int SPLIT = 2;                  // tile-halves per bucket in accum

constexpr size_t kRecBytes  = (size_t)TILES * RECS * 4;          // 256 MB
constexpr size_t kTblOff    = kRecBytes;
constexpr size_t kTblBytes  = ((size_t)TILES * TROW * 2 + 15) & ~(size_t)15;
constexpr size_t kAccOff    = kTblOff + kTblBytes;
constexpr size_t kAccBytes  = (size_t)SPLIT * kNodes * 4;        // 8 MB
constexpr size_t kOrcqOff   = kAccOff + kAccBytes;
constexpr size_t kOrcqBytes = (size_t)kNodes * 2;                // 2 MB
constexpr size_t kWsNeeded  = kOrcqOff + kOrcqBytes;             // ~270 MB

__global__ __launch_bounds__(256) void quant_orc(
        const float* __restrict__ orc, unsigned short* __restrict__ orcq) {
    const int i = (blockIdx.x * 256 + threadIdx.x) * 4;
    if (i >= kNodes) return;
    const float4 v = *reinterpret_cast<const float4*>(orc + i);
    unsigned q0 = __float2uint_rn((v.x + 1.0f) * 32768.0f);
    unsigned q1 = __float2uint_rn((v.y + 1.0f) * 32768.0f);
    unsigned q2 = __float2uint_rn((v.z + 1.0f) * 32768.0f);
    unsigned q3 = __float2uint_rn((v.w + 1.0f) * 32768.0f);
    q0 = q0 > 65535u ? 65535u : q0;
    q1 = q1 > 65535u ? 65535u : q1;
    q2 = q2 > 65535u ? 65535u : q2;
    q3 = q3 > 65535u ? 65535u : q3;
    ushort4 q;
    q.x = (unsigned short)q0; q.y = (unsigned short)q1;
    q.z = (unsigned short)q2; q.w = (unsigned short)q3;
    *reinterpret_cast<ushort4*>(orcq + i) = q;
}

__global__ __launch_bounds__(512, 8) void scatter_sort(
        const int* __restrict__ ei, const unsigned short* __restrict__ orcq,
        unsigned* __restrict__ rec, unsigned short* __restrict__ tbl) {
    __shared__ alignas(16) unsigned reorder[RECS];     // 32 KB
    __shared__ unsigned cnt[NB];                       // hist -> start -> cursor
    const int tid = threadIdx.x;
    const int t = blockIdx.x;
    const int e0 = t * EPT;
    const int ne = min(EPT, kEdges - e0);   // 4096; last tile 2048 (mult of 8)
    const int k8 = tid * 8;

    if (tid < NB) cnt[tid] = 0u;
    __syncthreads();

    // phase 1: 8 edges -> registers, 16 EARLY-ISSUED orcq gathers (latency
    // drains under histogram + scan), bucket histogram.
    int s[8], d[8];
    unsigned pq[8];                 // (q_for_d_rec << 16) | q_for_s_rec
    const bool act = k8 < ne;
    if (act) {
        const int4 sa = *reinterpret_cast<const int4*>(ei + e0 + k8);
        const int4 sb = *reinterpret_cast<const int4*>(ei + e0 + k8 + 4);
        const int4 da = *reinterpret_cast<const int4*>(ei + kEdges + e0 + k8);
        const int4 db = *reinterpret_cast<const int4*>(ei + kEdges + e0 + k8 + 4);
        s[0] = sa.x; s[1] = sa.y; s[2] = sa.z; s[3] = sa.w;
        s[4] = sb.x; s[5] = sb.y; s[6] = sb.z; s[7] = sb.w;
        d[0] = da.x; d[1] = da.y; d[2] = da.z; d[3] = da.w;
        d[4] = db.x; d[5] = db.y; d[6] = db.z; d[7] = db.w;
        #pragma unroll
        for (int j = 0; j < 8; ++j) {
            const unsigned a = orcq[d[j]];      // q(orc[d]) -> s-record
            const unsigned b = orcq[s[j]];      // q(orc[s]) -> d-record
            pq[j] = a | (b << 16);
        }
        #pragma unroll
        for (int j = 0; j < 8; ++j) {
            atomicAdd(&cnt[(unsigned)s[j] >> BSHIFT], 1u);
            atomicAdd(&cnt[(unsigned)d[j] >> BSHIFT], 1u);
        }
    }
    __syncthreads();

    // phase 2: wave-0 shuffle scan of raw counts (no padding); coalesced
    // [tile][bucket] table row write (514 contiguous bytes per tile).
    if (tid < 64) {
        const unsigned c0 = cnt[4 * tid + 0], c1 = cnt[4 * tid + 1];
        const unsigned c2 = cnt[4 * tid + 2], c3 = cnt[4 * tid + 3];
        const unsigned loc = c0 + c1 + c2 + c3;
        unsigned inc = loc;
        #pragma unroll
        for (int o = 1; o < 64; o <<= 1) {
            const unsigned v = (unsigned)__shfl_up((int)inc, o, 64);
            if (tid >= o) inc += v;
        }
        unsigned short* __restrict__ row = tbl + (size_t)t * TROW;
        unsigned base = inc - loc;
        cnt[4 * tid + 0] = base; row[4 * tid + 0] = (unsigned short)base;
        base += c0;
        cnt[4 * tid + 1] = base; row[4 * tid + 1] = (unsigned short)base;
        base += c1;
        cnt[4 * tid + 2] = base; row[4 * tid + 2] = (unsigned short)base;
        base += c2;
        cnt[4 * tid + 3] = base; row[4 * tid + 3] = (unsigned short)base;
        if (tid == 63) row[NB] = (unsigned short)(2 * ne);
    }
    __syncthreads();

    // phase 3: rank + scatter records into reorder buffer (from registers)
    if (act) {
        #pragma unroll
        for (int j = 0; j < 8; ++j) {
            const unsigned rs = atomicAdd(&cnt[(unsigned)s[j] >> BSHIFT], 1u);
            reorder[rs] = (((unsigned)s[j] & (BNODES - 1)) << 16) | (pq[j] & 0xFFFFu);
            const unsigned rd = atomicAdd(&cnt[(unsigned)d[j] >> BSHIFT], 1u);
            reorder[rd] = (((unsigned)d[j] & (BNODES - 1)) << 16) | (pq[j] >> 16);
        }
    }
    __syncthreads();

    // phase 4: coalesced full-line int4 flush of the sorted tile
    const int tot = 2 * ne;
    unsigned* __restrict__ g = rec + (size_t)t * RECS;
    for (int k = tid * 4; k < tot; k += 2048)
        *reinterpret_cast<int4*>(g + k) = *reinterpret_cast<const int4*>(reorder + k);
}

__global__ __launch_bounds__(1024) void bucket_accum(
        const unsigned* __restrict__ rec, const unsigned short* __restrict__ tbl,
        unsigned* __restrict__ acc) {
    __shared__ unsigned lacc[BNODES];             // 16 KB
    const int tid = threadIdx.x;
    const int b = blockIdx.x >> 1;
    const int half = blockIdx.x & 1;
    for (int k = tid; k < BNODES; k += 1024) lacc[k] = 0u;
    __syncthreads();
    constexpr int TPS = (TILES + SPLIT - 1) / SPLIT;  // 3907
    const int t0 = half * TPS;
    const int t1 = min(TILES, t0 + TPS);
    const int wid = tid >> 6;                     // 16 waves
    const int lane = tid & 63;
    // one wave per (bucket,tile) segment: lanes read CONSECUTIVE records
    for (int t = t0 + wid; t < t1; t += 16) {
        const unsigned short* __restrict__ row = tbl + (size_t)t * TROW + b;
        const unsigned st = row[0];
        const unsigned en = row[1];
        const unsigned* __restrict__ p = rec + (size_t)t * RECS;
        for (unsigned k = st + lane; k < en; k += 64) {
            const unsigned v = p[k];
            // deg in bits [24,32), sum(q16) in [0,24)
            atomicAdd(&lacc[v >> 16], (v & 0xFFFFu) | 0x1000000u);
        }
    }
    __syncthreads();
    const int base = b << BSHIFT;
    unsigned* __restrict__ dst = acc + (size_t)half * kNodes;
    for (int k = tid; k < BNODES; k += 1024) {
        const int nn = base + k;
        if (nn < kNodes) dst[nn] = lacc[k];
    }
}

// ---------------- Fallback (atomic) path ----------------
constexpr float kScale = 1048576.0f;           // 2^20
constexpr float kInvScale = 1.0f / 1048576.0f;
constexpr long long kBias = 1ll << 36;

__global__ __launch_bounds__(256) void zero_acc(unsigned long long* __restrict__ acc) {
    int i = blockIdx.x * 256 + threadIdx.x;
    if (i < kNodes) acc[i] = 0ull;
}

__global__ __launch_bounds__(256) void edge_kernel(
        const int* __restrict__ ei,
        const float* __restrict__ orc,
        unsigned long long* __restrict__ acc) {
    int t = blockIdx.x * 256 + threadIdx.x;
    int e0 = t * 4;
    if (e0 >= kEdges) return;
    const int4 s4 = *reinterpret_cast<const int4*>(ei + e0);
    const int4 d4 = *reinterpret_cast<const int4*>(ei + kEdges + e0);
    const int ss[4] = {s4.x, s4.y, s4.z, s4.w};
    const int dd[4] = {d4.x, d4.y, d4.z, d4.w};
    #pragma unroll
    for (int k = 0; k < 4; ++k) {
        const float os = orc[ss[k]];
        const float od = orc[dd[k]];
        const unsigned long long ps =
            (1ull << 48) + (unsigned long long)(kBias + (long long)__float2ll_rn(od * kScale));
        const unsigned long long pd =
            (1ull << 48) + (unsigned long long)(kBias + (long long)__float2ll_rn(os * kScale));
        atomicAdd(&acc[ss[k]], ps);
        atomicAdd(&acc[dd[k]], pd);
    }
}

// ---------------- Node phase ----------------
// MODE 0: deg<<48 | biased 2^20 fixed sum (u64).
// MODE 3: two u32 partials, each deg<<24 | sum(q16).
template <int MODE>
__global__ __launch_bounds__(256) void node_kernel(
        const float* __restrict__ orc,
        const unsigned long long* __restrict__ acc64,
        const unsigned* __restrict__ acc32,
        const float* __restrict__ W1, const float* __restrict__ b1,
        const float* __restrict__ W2, const float* __restrict__ b2,
        const float* __restrict__ gamma, const float* __restrict__ beta,
        float* __restrict__ out) {
    const int i = blockIdx.x * 256 + threadIdx.x;
    if (i >= kNodes) return;

    const float x0 = orc[i];
    float nb;
    if (MODE == 0) {
        const unsigned long long p = acc64[i];
        const unsigned deg = (unsigned)(p >> 48);
        const long long sf = (long long)(p & ((1ull << 48) - 1)) - (long long)deg * kBias;
        const float s = (float)sf * kInvScale;
        nb = (deg > 0) ? s / (float)deg : 0.0f;
    } else {
        const unsigned p0 = acc32[i];
        const unsigned p1 = acc32[kNodes + i];
        const unsigned deg = (p0 >> 24) + (p1 >> 24);
        const unsigned sumq = (p0 & 0xFFFFFFu) + (p1 & 0xFFFFFFu);
        nb = (deg > 0)
            ? ((float)sumq * (1.0f / 32768.0f) / (float)deg - 1.0f) : 0.0f;
    }

    constexpr float kPi = 3.14159265358979323846f;
    float Phi[16];
    const float n0 = __saturatef((x0 + 1.0f) * 0.5f);
    const float n1 = __saturatef((nb + 1.0f) * 0.5f);
    #pragma unroll
    for (int k = 0; k < 4; ++k) {
        const float a0 = n0 * (float)(k + 1) * kPi;
        const float a1 = n1 * (float)(k + 1) * kPi;
        Phi[2 * k]     = __sinf(a0);
        Phi[2 * k + 1] = __cosf(a0);
        Phi[8 + 2 * k]     = __sinf(a1);
        Phi[8 + 2 * k + 1] = __cosf(a1);
    }

    float y[16];
    #pragma unroll
    for (int d = 0; d < 16; ++d) y[d] = b2[d];
    #pragma unroll
    for (int j = 0; j < 32; ++j) {
        float a = b1[j];
        #pragma unroll
        for (int d = 0; d < 16; ++d) a = fmaf(Phi[d], W1[j * 16 + d], a);
        a = fmaxf(a, 0.0f);
        #pragma unroll
        for (int d = 0; d < 16; ++d) y[d] = fmaf(a, W2[d * 32 + j], y[d]);
    }

    float mu = 0.0f;
    #pragma unroll
    for (int d = 0; d < 16; ++d) mu += y[d];
    mu *= (1.0f / 16.0f);
    float var = 0.0f;
    #pragma unroll
    for (int d = 0; d < 16; ++d) { const float t = y[d] - mu; var = fmaf(t, t, var); }
    var *= (1.0f / 16.0f);
    const float inv = rsqrtf(var + 1e-5f);

    float4* o4 = reinterpret_cast<float4*>(out + (size_t)i * 16);
    #pragma unroll
    for (int q = 0; q < 4; ++q) {
        float4 o;
        o.x = (y[4 * q + 0] - mu) * inv * gamma[4 * q + 0] + beta[4 * q + 0] + Phi[4 * q + 0];
        o.y = (y[4 * q + 1] - mu) * inv * gamma[4 * q + 1] + beta[4 * q + 1] + Phi[4 * q + 1];
        o.z = (y[4 * q + 2] - mu) * inv * gamma[4 * q + 2] + beta[4 * q + 2] + Phi[4 * q + 2];
        o.w = (y[4 * q + 3] - mu) * inv * gamma[4 * q + 3] + beta[4 * q + 3] + Phi[4 * q + 3];
        o4[q] = o;
    }
}

extern "C" void kernel_launch(void* const* d_in, const int* in_sizes, int n_in,
                              void* d_out, int out_size, void* d_ws, size_t ws_size,
                              hipStream_t stream) {
    const float* orc   = (const float*)d_in[0];
    const int*   ei    = (const int*)d_in[1];
    const float* W1    = (const float*)d_in[2];
    const float* b1    = (const float*)d_in[3];
    const float* W2    = (const float*)d_in[4];
    const float* b2    = (const float*)d_in[5];
    const float* gamma = (const float*)d_in[6];
    const float* beta  = (const float*)d_in[7];
    float* out = (float*)d_out;
    char* ws = (char*)d_ws;

    if (ws_size >= kWsNeeded) {
        unsigned* rec = (unsigned*)ws;
        unsigned short* tbl = (unsigned short*)(ws + kTblOff);
        unsigned* acc = (unsigned*)(ws + kAccOff);
        unsigned short* orcq = (unsigned short*)(ws + kOrcqOff);
        quant_orc<<<(kNodes / 4 + 255) / 256, 256, 0, stream>>>(orc, orcq);
        scatter_sort<<<TILES, 512, 0, stream>>>(ei, orcq, rec, tbl);
        bucket_accum<<<NBUSED * SPLIT, 1024, 0, stream>>>(rec, tbl, acc);
        node_kernel<3><<<(kNodes + 255) / 256, 256, 0, stream>>>(
            orc, nullptr, acc, W1, b1, W2, b2, gamma, beta, out);
    } else {
        unsigned long long* acc = (unsigned long long*)ws;  // 8 MB
        zero_acc<<<(kNodes + 255) / 256, 256, 0, stream>>>(acc);
        edge_kernel<<<(kEdges / 4 + 255) / 256, 256, 0, stream>>>(ei, orc, acc);
        node_kernel<0><<<(kNodes + 255) / 256, 256, 0, stream>>>(
            orc, acc, nullptr, W1, b1, W2, b2, gamma, beta, out);
    }
}

// Round 4
// 727.966 us; speedup vs baseline: 1.3906x; 1.2403x over previous
//
#include <hip/hip_runtime.h>

constexpr int kNodes = 1000000;
constexpr int kEdges = 32000000;

// ---------------- Tile-sorted scatter path (aligned arena) ----------------
// 256 buckets x 4096 nodes. Record u32 = (node&4095)<<16 | q16,
// q16 = clamp(round((orc_other+1)*32768), 0, 65535)  (error <= 1.5e-5).
// Producer: per 4096-edge tile, LDS counting sort by bucket with per-bucket
// segments PADDED to multiples of 4 records (pad = PADREC) so every int4
// group belongs to exactly one bucket. Wave-0 allocates each tile's padded
// segments in per-bucket global arenas via one atomicAdd per bucket (issued
// before the rank phase -> round trip hidden), at 16B-aligned offsets.
// Flush = full-line int4 stores to near-contiguous per-bucket runs.
// Consumer: one block-pair per bucket streams the dense arena region with
// coalesced uint4 loads; pad records route to a dummy LDS sink (no branch).
constexpr int NB = 256;
constexpr int BSHIFT = 12;
constexpr int BNODES = 4096;
constexpr int NBUSED = (kNodes + BNODES - 1) / BNODES;   // 245
constexpr int EPT = 4096;                 // edges per tile
constexpr int LSIZE = 8960;               // max padded records/tile (8192+256*3)
constexpr int TILES = (kEdges + EPT - 1) / EPT;          // 7813
constexpr int CAP = 284672;               // per-bucket capacity (mult of 4);
                                          // padded mean ~272.7K, sigma~508 -> 23 sigma
constexpr int SPLIT = 2;
constexpr unsigned PADREC = 0x10000000u;  // local node 4096 -> LDS sink slot

constexpr size_t kArenaBytes = (size_t)NBUSED * CAP * 4;   // ~279 MB
constexpr size_t kCurOff    = kArenaBytes;
constexpr size_t kCurBytes  = (size_t)NB * 64;             // 1 cursor per 64B line
constexpr size_t kAccOff    = kCurOff + kCurBytes;
constexpr size_t kAccBytes  = (size_t)SPLIT * kNodes * 4;  // 8 MB
constexpr size_t kOrcqOff   = kAccOff + kAccBytes;
constexpr size_t kOrcqBytes = (size_t)kNodes * 2;          // 2 MB
constexpr size_t kWsNeeded  = kOrcqOff + kOrcqBytes;       // ~289 MB

__global__ __launch_bounds__(256) void quant_orc(
        const float* __restrict__ orc, unsigned short* __restrict__ orcq,
        unsigned* __restrict__ gcur) {
    if (blockIdx.x == 0 && threadIdx.x < NB) gcur[threadIdx.x * 16] = 0u;
    const int i = (blockIdx.x * 256 + threadIdx.x) * 4;
    if (i >= kNodes) return;
    const float4 v = *reinterpret_cast<const float4*>(orc + i);
    unsigned q0 = __float2uint_rn((v.x + 1.0f) * 32768.0f);
    unsigned q1 = __float2uint_rn((v.y + 1.0f) * 32768.0f);
    unsigned q2 = __float2uint_rn((v.z + 1.0f) * 32768.0f);
    unsigned q3 = __float2uint_rn((v.w + 1.0f) * 32768.0f);
    q0 = q0 > 65535u ? 65535u : q0;
    q1 = q1 > 65535u ? 65535u : q1;
    q2 = q2 > 65535u ? 65535u : q2;
    q3 = q3 > 65535u ? 65535u : q3;
    ushort4 q;
    q.x = (unsigned short)q0; q.y = (unsigned short)q1;
    q.z = (unsigned short)q2; q.w = (unsigned short)q3;
    *reinterpret_cast<ushort4*>(orcq + i) = q;
}

__global__ __launch_bounds__(1024) void scatter_sort(
        const int* __restrict__ ei, const unsigned short* __restrict__ orcq,
        unsigned* __restrict__ arena, unsigned* __restrict__ gcur) {
    __shared__ alignas(16) unsigned reorder[LSIZE];     // 35 KB
    __shared__ unsigned char gb[LSIZE / 4];             // bucket per int4 group
    __shared__ unsigned cnt[NB];                        // hist -> P -> cursor
    __shared__ unsigned pend[NB];                       // P + pc (padded end)
    __shared__ unsigned dstadd[NB];                     // b*CAP + g - P
    const int tid = threadIdx.x;
    const int t = blockIdx.x;
    const int e0 = t * EPT;
    const int ne = min(EPT, kEdges - e0);   // 4096; last tile 2048
    const int k4 = tid * 4;

    if (tid < NB) cnt[tid] = 0u;
    __syncthreads();

    // phase 1: 4 edges -> registers, 8 EARLY-ISSUED orcq gathers (latency
    // drains under histogram + scan), bucket histogram.
    int4 s4, d4;
    s4.x = s4.y = s4.z = s4.w = 0; d4 = s4;
    unsigned pq0 = 0, pq1 = 0, pq2 = 0, pq3 = 0;  // (q_for_d_rec<<16)|q_for_s_rec
    const bool act = k4 < ne;
    if (act) {
        s4 = *reinterpret_cast<const int4*>(ei + e0 + k4);
        d4 = *reinterpret_cast<const int4*>(ei + kEdges + e0 + k4);
        const unsigned a0 = orcq[d4.x], a1 = orcq[d4.y],
                       a2 = orcq[d4.z], a3 = orcq[d4.w];
        const unsigned b0 = orcq[s4.x], b1 = orcq[s4.y],
                       b2 = orcq[s4.z], b3 = orcq[s4.w];
        atomicAdd(&cnt[(unsigned)s4.x >> BSHIFT], 1u);
        atomicAdd(&cnt[(unsigned)s4.y >> BSHIFT], 1u);
        atomicAdd(&cnt[(unsigned)s4.z >> BSHIFT], 1u);
        atomicAdd(&cnt[(unsigned)s4.w >> BSHIFT], 1u);
        atomicAdd(&cnt[(unsigned)d4.x >> BSHIFT], 1u);
        atomicAdd(&cnt[(unsigned)d4.y >> BSHIFT], 1u);
        atomicAdd(&cnt[(unsigned)d4.z >> BSHIFT], 1u);
        atomicAdd(&cnt[(unsigned)d4.w >> BSHIFT], 1u);
        pq0 = a0 | (b0 << 16);
        pq1 = a1 | (b1 << 16);
        pq2 = a2 | (b2 << 16);
        pq3 = a3 | (b3 << 16);
    }
    __syncthreads();

    // phase 2: wave-0 shuffle scan of PADDED counts; issue per-bucket arena
    // cursor atomics now (results consumed after the rank phase).
    unsigned P0 = 0, P1 = 0, P2 = 0, P3 = 0;
    unsigned g0 = 0, g1 = 0, g2 = 0, g3 = 0;
    unsigned pc0 = 0, pc1 = 0, pc2 = 0, pc3 = 0;
    if (tid < 64) {
        const unsigned c0 = cnt[4 * tid + 0], c1 = cnt[4 * tid + 1];
        const unsigned c2 = cnt[4 * tid + 2], c3 = cnt[4 * tid + 3];
        pc0 = (c0 + 3u) & ~3u; pc1 = (c1 + 3u) & ~3u;
        pc2 = (c2 + 3u) & ~3u; pc3 = (c3 + 3u) & ~3u;
        const unsigned loc = pc0 + pc1 + pc2 + pc3;
        unsigned inc = loc;
        #pragma unroll
        for (int o = 1; o < 64; o <<= 1) {
            const unsigned v = (unsigned)__shfl_up((int)inc, o, 64);
            if (tid >= o) inc += v;
        }
        P0 = inc - loc; P1 = P0 + pc0; P2 = P1 + pc1; P3 = P2 + pc2;
        cnt[4 * tid + 0] = P0; pend[4 * tid + 0] = P1;
        cnt[4 * tid + 1] = P1; pend[4 * tid + 1] = P2;
        cnt[4 * tid + 2] = P2; pend[4 * tid + 2] = P3;
        cnt[4 * tid + 3] = P3; pend[4 * tid + 3] = P3 + pc3;
        g0 = atomicAdd(&gcur[(4 * tid + 0) * 16], pc0);
        g1 = atomicAdd(&gcur[(4 * tid + 1) * 16], pc1);
        g2 = atomicAdd(&gcur[(4 * tid + 2) * 16], pc2);
        g3 = atomicAdd(&gcur[(4 * tid + 3) * 16], pc3);
    }
    __syncthreads();

    // phase 3: rank + scatter records into reorder buffer (from registers);
    // record the bucket of each int4 group (groups never straddle buckets).
    if (act) {
        #define RANK1(S, D, PQ) { \
            const unsigned bs_ = (unsigned)(S) >> BSHIFT; \
            const unsigned rs_ = atomicAdd(&cnt[bs_], 1u); \
            reorder[rs_] = (((unsigned)(S) & (BNODES - 1)) << 16) | ((PQ) & 0xFFFFu); \
            gb[rs_ >> 2] = (unsigned char)bs_; \
            const unsigned bd_ = (unsigned)(D) >> BSHIFT; \
            const unsigned rd_ = atomicAdd(&cnt[bd_], 1u); \
            reorder[rd_] = (((unsigned)(D) & (BNODES - 1)) << 16) | ((PQ) >> 16); \
            gb[rd_ >> 2] = (unsigned char)bd_; }
        RANK1(s4.x, d4.x, pq0)
        RANK1(s4.y, d4.y, pq1)
        RANK1(s4.z, d4.z, pq2)
        RANK1(s4.w, d4.w, pq3)
        #undef RANK1
    }
    __syncthreads();

    // phase 2b: arena dst bases (wave-0 regs; u32 wrap arithmetic is exact);
    // fill the <=3 pad slots at each bucket segment's tail.
    if (tid < 64) {
        if (g0 + pc0 > (unsigned)CAP) g0 = CAP - pc0;   // 23-sigma safety clamp
        if (g1 + pc1 > (unsigned)CAP) g1 = CAP - pc1;
        if (g2 + pc2 > (unsigned)CAP) g2 = CAP - pc2;
        if (g3 + pc3 > (unsigned)CAP) g3 = CAP - pc3;
        dstadd[4 * tid + 0] = (unsigned)(4 * tid + 0) * CAP + g0 - P0;
        dstadd[4 * tid + 1] = (unsigned)(4 * tid + 1) * CAP + g1 - P1;
        dstadd[4 * tid + 2] = (unsigned)(4 * tid + 2) * CAP + g2 - P2;
        dstadd[4 * tid + 3] = (unsigned)(4 * tid + 3) * CAP + g3 - P3;
    }
    if (tid < NB) {
        const unsigned e = pend[tid];
        for (unsigned k = cnt[tid]; k < e; ++k) reorder[k] = PADREC;
    }
    __syncthreads();

    // phase 4: full-line int4 flush to 16B-aligned arena positions.
    // Consecutive groups are same-bucket runs (~8 groups), near-contiguous.
    const unsigned tot = pend[NB - 1];
    for (unsigned k = (unsigned)k4; k < tot; k += 4096) {
        const unsigned bb = gb[k >> 2];
        *reinterpret_cast<int4*>(arena + dstadd[bb] + k) =
            *reinterpret_cast<const int4*>(reorder + k);
    }
}

__global__ __launch_bounds__(1024) void bucket_accum(
        const unsigned* __restrict__ arena, const unsigned* __restrict__ gcur,
        unsigned* __restrict__ acc) {
    __shared__ unsigned lacc[BNODES + 4];        // slot 4096 = pad sink
    const int tid = threadIdx.x;
    const int b = blockIdx.x >> 1;
    const int half = blockIdx.x & 1;
    for (int k = tid; k < BNODES + 4; k += 1024) lacc[k] = 0u;
    __syncthreads();
    const unsigned len = gcur[b * 16];           // padded records, mult of 4
    const unsigned h = (len >> 1) & ~3u;
    const unsigned lo4 = (half ? h : 0u) >> 2;
    const unsigned hi4 = (half ? len : h) >> 2;
    const uint4* __restrict__ p =
        reinterpret_cast<const uint4*>(arena + (size_t)b * CAP);
    for (unsigned i = lo4 + tid; i < hi4; i += 1024) {
        const uint4 v = p[i];
        // deg in bits [24,32), sum(q16) in [0,24); PADREC -> lacc[4096]
        atomicAdd(&lacc[v.x >> 16], (v.x & 0xFFFFu) | 0x1000000u);
        atomicAdd(&lacc[v.y >> 16], (v.y & 0xFFFFu) | 0x1000000u);
        atomicAdd(&lacc[v.z >> 16], (v.z & 0xFFFFu) | 0x1000000u);
        atomicAdd(&lacc[v.w >> 16], (v.w & 0xFFFFu) | 0x1000000u);
    }
    __syncthreads();
    const int base = b << BSHIFT;
    unsigned* __restrict__ dst = acc + (size_t)half * kNodes;
    for (int k = tid; k < BNODES; k += 1024) {
        const int nn = base + k;
        if (nn < kNodes) dst[nn] = lacc[k];
    }
}

// ---------------- Fallback (atomic) path ----------------
constexpr float kScale = 1048576.0f;           // 2^20
constexpr float kInvScale = 1.0f / 1048576.0f;
constexpr long long kBias = 1ll << 36;

__global__ __launch_bounds__(256) void zero_acc(unsigned long long* __restrict__ acc) {
    int i = blockIdx.x * 256 + threadIdx.x;
    if (i < kNodes) acc[i] = 0ull;
}

__global__ __launch_bounds__(256) void edge_kernel(
        const int* __restrict__ ei,
        const float* __restrict__ orc,
        unsigned long long* __restrict__ acc) {
    int t = blockIdx.x * 256 + threadIdx.x;
    int e0 = t * 4;
    if (e0 >= kEdges) return;
    const int4 s4 = *reinterpret_cast<const int4*>(ei + e0);
    const int4 d4 = *reinterpret_cast<const int4*>(ei + kEdges + e0);
    const int ss[4] = {s4.x, s4.y, s4.z, s4.w};
    const int dd[4] = {d4.x, d4.y, d4.z, d4.w};
    #pragma unroll
    for (int k = 0; k < 4; ++k) {
        const float os = orc[ss[k]];
        const float od = orc[dd[k]];
        const unsigned long long ps =
            (1ull << 48) + (unsigned long long)(kBias + (long long)__float2ll_rn(od * kScale));
        const unsigned long long pd =
            (1ull << 48) + (unsigned long long)(kBias + (long long)__float2ll_rn(os * kScale));
        atomicAdd(&acc[ss[k]], ps);
        atomicAdd(&acc[dd[k]], pd);
    }
}

// ---------------- Node phase ----------------
// MODE 0: deg<<48 | biased 2^20 fixed sum (u64).
// MODE 3: two u32 partials, each deg<<24 | sum(q16).
template <int MODE>
__global__ __launch_bounds__(256) void node_kernel(
        const float* __restrict__ orc,
        const unsigned long long* __restrict__ acc64,
        const unsigned* __restrict__ acc32,
        const float* __restrict__ W1, const float* __restrict__ b1,
        const float* __restrict__ W2, const float* __restrict__ b2,
        const float* __restrict__ gamma, const float* __restrict__ beta,
        float* __restrict__ out) {
    const int i = blockIdx.x * 256 + threadIdx.x;
    if (i >= kNodes) return;

    const float x0 = orc[i];
    float nb;
    if (MODE == 0) {
        const unsigned long long p = acc64[i];
        const unsigned deg = (unsigned)(p >> 48);
        const long long sf = (long long)(p & ((1ull << 48) - 1)) - (long long)deg * kBias;
        const float s = (float)sf * kInvScale;
        nb = (deg > 0) ? s / (float)deg : 0.0f;
    } else {
        const unsigned p0 = acc32[i];
        const unsigned p1 = acc32[kNodes + i];
        const unsigned deg = (p0 >> 24) + (p1 >> 24);
        const unsigned sumq = (p0 & 0xFFFFFFu) + (p1 & 0xFFFFFFu);
        nb = (deg > 0)
            ? ((float)sumq * (1.0f / 32768.0f) / (float)deg - 1.0f) : 0.0f;
    }

    constexpr float kPi = 3.14159265358979323846f;
    float Phi[16];
    const float n0 = __saturatef((x0 + 1.0f) * 0.5f);
    const float n1 = __saturatef((nb + 1.0f) * 0.5f);
    #pragma unroll
    for (int k = 0; k < 4; ++k) {
        const float a0 = n0 * (float)(k + 1) * kPi;
        const float a1 = n1 * (float)(k + 1) * kPi;
        Phi[2 * k]     = __sinf(a0);
        Phi[2 * k + 1] = __cosf(a0);
        Phi[8 + 2 * k]     = __sinf(a1);
        Phi[8 + 2 * k + 1] = __cosf(a1);
    }

    float y[16];
    #pragma unroll
    for (int d = 0; d < 16; ++d) y[d] = b2[d];
    #pragma unroll
    for (int j = 0; j < 32; ++j) {
        float a = b1[j];
        #pragma unroll
        for (int d = 0; d < 16; ++d) a = fmaf(Phi[d], W1[j * 16 + d], a);
        a = fmaxf(a, 0.0f);
        #pragma unroll
        for (int d = 0; d < 16; ++d) y[d] = fmaf(a, W2[d * 32 + j], y[d]);
    }

    float mu = 0.0f;
    #pragma unroll
    for (int d = 0; d < 16; ++d) mu += y[d];
    mu *= (1.0f / 16.0f);
    float var = 0.0f;
    #pragma unroll
    for (int d = 0; d < 16; ++d) { const float t = y[d] - mu; var = fmaf(t, t, var); }
    var *= (1.0f / 16.0f);
    const float inv = rsqrtf(var + 1e-5f);

    float4* o4 = reinterpret_cast<float4*>(out + (size_t)i * 16);
    #pragma unroll
    for (int q = 0; q < 4; ++q) {
        float4 o;
        o.x = (y[4 * q + 0] - mu) * inv * gamma[4 * q + 0] + beta[4 * q + 0] + Phi[4 * q + 0];
        o.y = (y[4 * q + 1] - mu) * inv * gamma[4 * q + 1] + beta[4 * q + 1] + Phi[4 * q + 1];
        o.z = (y[4 * q + 2] - mu) * inv * gamma[4 * q + 2] + beta[4 * q + 2] + Phi[4 * q + 2];
        o.w = (y[4 * q + 3] - mu) * inv * gamma[4 * q + 3] + beta[4 * q + 3] + Phi[4 * q + 3];
        o4[q] = o;
    }
}

extern "C" void kernel_launch(void* const* d_in, const int* in_sizes, int n_in,
                              void* d_out, int out_size, void* d_ws, size_t ws_size,
                              hipStream_t stream) {
    const float* orc   = (const float*)d_in[0];
    const int*   ei    = (const int*)d_in[1];
    const float* W1    = (const float*)d_in[2];
    const float* b1    = (const float*)d_in[3];
    const float* W2    = (const float*)d_in[4];
    const float* b2    = (const float*)d_in[5];
    const float* gamma = (const float*)d_in[6];
    const float* beta  = (const float*)d_in[7];
    float* out = (float*)d_out;
    char* ws = (char*)d_ws;

    if (ws_size >= kWsNeeded) {
        unsigned* arena = (unsigned*)ws;
        unsigned* gcur = (unsigned*)(ws + kCurOff);
        unsigned* acc = (unsigned*)(ws + kAccOff);
        unsigned short* orcq = (unsigned short*)(ws + kOrcqOff);
        quant_orc<<<(kNodes / 4 + 255) / 256, 256, 0, stream>>>(orc, orcq, gcur);
        scatter_sort<<<TILES, 1024, 0, stream>>>(ei, orcq, arena, gcur);
        bucket_accum<<<NBUSED * SPLIT, 1024, 0, stream>>>(arena, gcur, acc);
        node_kernel<3><<<(kNodes + 255) / 256, 256, 0, stream>>>(
            orc, nullptr, acc, W1, b1, W2, b2, gamma, beta, out);
    } else {
        unsigned long long* acc = (unsigned long long*)ws;  // 8 MB
        zero_acc<<<(kNodes + 255) / 256, 256, 0, stream>>>(acc);
        edge_kernel<<<(kEdges / 4 + 255) / 256, 256, 0, stream>>>(ei, orc, acc);
        node_kernel<0><<<(kNodes + 255) / 256, 256, 0, stream>>>(
            orc, acc, nullptr, W1, b1, W2, b2, gamma, beta, out);
    }
}

// Round 5
// 708.919 us; speedup vs baseline: 1.4280x; 1.0269x over previous
//
#include <hip/hip_runtime.h>

constexpr int kNodes = 1000000;
constexpr int kEdges = 32000000;

// ---------------- Tile-sorted scatter path (slab + arena) ----------------
// 256 buckets x 4096 nodes. Record u32 = (node&4095)<<16 | q16,
// q16 = clamp(round((orc_other+1)*32768), 0, 65535)  (error <= 1.5e-5).
// Producer (per 4096-edge tile): NO histogram pass. Each bucket has a fixed
// 72-slot LDS slab; rank atomic r=atomicAdd(cnt[b]) places the record at
// slab[b*72+r] directly (one LDS atomic per record instead of two).
// P(count>72)~7e-8 per segment (Poisson 33.6) -> ~0.13 expected overflows
// total, routed exactly via a global overflow list + fixup kernel.
// Arena allocation needs no scan: per-bucket atomicAdd(gcur[b], paddedcount)
// gives each tile a 16B-aligned contiguous run in that bucket's region.
// Consumer: one block-pair per bucket streams the dense arena region with
// coalesced uint4 loads into DUAL LDS accumulator copies (wave parity picks
// the copy -> halves bank/address collisions); pads hit a sink slot.
constexpr int NB = 256;
constexpr int BSHIFT = 12;
constexpr int BNODES = 4096;
constexpr int NBUSED = (kNodes + BNODES - 1) / BNODES;   // 245
constexpr int EPT = 4096;                 // edges per tile
constexpr int TILES = (kEdges + EPT - 1) / EPT;          // 7813
constexpr int SLOT = 72;                  // LDS slab slots per bucket
constexpr int GP = SLOT / 4;              // int4 groups per slab (18)
constexpr int CAP = 284672;               // per-bucket arena capacity (mult 4)
                                          // padded mean ~272.7K, 23 sigma
constexpr int SPLIT = 2;
constexpr unsigned PADREC = 0x10000000u;  // local node 4096 -> LDS sink slot
constexpr unsigned OVFCAP = 8192;

constexpr size_t kArenaBytes = (size_t)NBUSED * CAP * 4;   // ~279 MB
constexpr size_t kCurOff    = kArenaBytes;
constexpr size_t kCurBytes  = (size_t)NB * 64 + 64;        // strided cursors + ovfcnt
constexpr size_t kAccOff    = kCurOff + kCurBytes;
constexpr size_t kAccBytes  = (size_t)SPLIT * kNodes * 4;  // 8 MB
constexpr size_t kOrcqOff   = kAccOff + kAccBytes;
constexpr size_t kOrcqBytes = (size_t)kNodes * 2;          // 2 MB
constexpr size_t kOvfOff    = (kOrcqOff + kOrcqBytes + 7) & ~(size_t)7;
constexpr size_t kOvfBytes  = (size_t)OVFCAP * 8;          // 64 KB
constexpr size_t kWsNeeded  = kOvfOff + kOvfBytes;         // ~289 MB

__global__ __launch_bounds__(256) void quant_orc(
        const float* __restrict__ orc, unsigned short* __restrict__ orcq,
        unsigned* __restrict__ gcur) {
    if (blockIdx.x == 0) {
        if (threadIdx.x < NB) gcur[threadIdx.x * 16] = 0u;
        if (threadIdx.x == 0) gcur[NB * 16] = 0u;       // overflow counter
    }
    const int i = (blockIdx.x * 256 + threadIdx.x) * 4;
    if (i >= kNodes) return;
    const float4 v = *reinterpret_cast<const float4*>(orc + i);
    unsigned q0 = __float2uint_rn((v.x + 1.0f) * 32768.0f);
    unsigned q1 = __float2uint_rn((v.y + 1.0f) * 32768.0f);
    unsigned q2 = __float2uint_rn((v.z + 1.0f) * 32768.0f);
    unsigned q3 = __float2uint_rn((v.w + 1.0f) * 32768.0f);
    q0 = q0 > 65535u ? 65535u : q0;
    q1 = q1 > 65535u ? 65535u : q1;
    q2 = q2 > 65535u ? 65535u : q2;
    q3 = q3 > 65535u ? 65535u : q3;
    ushort4 q;
    q.x = (unsigned short)q0; q.y = (unsigned short)q1;
    q.z = (unsigned short)q2; q.w = (unsigned short)q3;
    *reinterpret_cast<ushort4*>(orcq + i) = q;
}

__global__ __launch_bounds__(1024) void scatter_sort(
        const int* __restrict__ ei, const unsigned short* __restrict__ orcq,
        unsigned* __restrict__ arena, unsigned* __restrict__ gcur,
        unsigned long long* __restrict__ ovf) {
    __shared__ alignas(16) unsigned slab[NB * SLOT];   // 72 KB fixed slabs
    __shared__ unsigned cnt[NB];                       // rank cursors
    __shared__ unsigned pcs[NB];                       // padded counts
    __shared__ unsigned dstadd[NB];                    // arena dst base
    const int tid = threadIdx.x;
    const int t = blockIdx.x;
    const int e0 = t * EPT;
    const int ne = min(EPT, kEdges - e0);   // 4096; last tile 2048
    const int k4 = tid * 4;

    if (tid < NB) cnt[tid] = 0u;
    __syncthreads();

    // phase 1: edges -> registers, orcq gathers, rank + slab store.
    // ONE LDS atomic per record (no histogram pass).
    if (k4 < ne) {
        const int4 s4 = *reinterpret_cast<const int4*>(ei + e0 + k4);
        const int4 d4 = *reinterpret_cast<const int4*>(ei + kEdges + e0 + k4);
        const unsigned a0 = orcq[d4.x], a1 = orcq[d4.y],
                       a2 = orcq[d4.z], a3 = orcq[d4.w];   // q(orc[d]) -> s-rec
        const unsigned b0 = orcq[s4.x], b1 = orcq[s4.y],
                       b2 = orcq[s4.z], b3 = orcq[s4.w];   // q(orc[s]) -> d-rec
        #define RANK1(N, Q) { \
            const unsigned b_ = (unsigned)(N) >> BSHIFT; \
            const unsigned r_ = atomicAdd(&cnt[b_], 1u); \
            if (r_ < (unsigned)SLOT) { \
                slab[b_ * SLOT + r_] = (((unsigned)(N) & (BNODES - 1)) << 16) | (Q); \
            } else { \
                const unsigned oi_ = atomicAdd(&gcur[NB * 16], 1u); \
                if (oi_ < OVFCAP) \
                    ovf[oi_] = ((unsigned long long)(unsigned)(N) << 16) | (Q); \
            } }
        RANK1(s4.x, a0) RANK1(s4.y, a1) RANK1(s4.z, a2) RANK1(s4.w, a3)
        RANK1(d4.x, b0) RANK1(d4.y, b1) RANK1(d4.z, b2) RANK1(d4.w, b3)
        #undef RANK1
    }
    __syncthreads();

    // phase 2: per-bucket arena allocation (independent atomics, no scan),
    // pad fill to multiple of 4 records so every int4 group is one bucket.
    if (tid < NB) {
        unsigned c = cnt[tid];
        c = c > (unsigned)SLOT ? (unsigned)SLOT : c;
        const unsigned pc = (c + 3u) & ~3u;
        pcs[tid] = pc;
        unsigned g = atomicAdd(&gcur[tid * 16], pc);
        if (g + pc > (unsigned)CAP) g = CAP - pc;   // 23-sigma safety clamp
        dstadd[tid] = (unsigned)tid * CAP + g;
        for (unsigned j = c; j < pc; ++j) slab[tid * SLOT + j] = PADREC;
    }
    __syncthreads();

    // phase 3: int4 flush of live groups to 16B-aligned arena positions
    for (int k = tid; k < NB * GP; k += 1024) {
        const int b = k / GP;
        const int g4 = (k - b * GP) * 4;
        if ((unsigned)g4 < pcs[b]) {
            *reinterpret_cast<int4*>(arena + dstadd[b] + g4) =
                *reinterpret_cast<const int4*>(slab + b * SLOT + g4);
        }
    }
}

__global__ __launch_bounds__(1024) void bucket_accum(
        const unsigned* __restrict__ arena, const unsigned* __restrict__ gcur,
        unsigned* __restrict__ acc) {
    __shared__ unsigned lacc[2][BNODES + 4];     // dual copies; slot 4096 = sink
    const int tid = threadIdx.x;
    const int b = blockIdx.x >> 1;
    const int half = blockIdx.x & 1;
    for (int k = tid; k < 2 * (BNODES + 4); k += 1024)
        lacc[0][k] = 0u;                          // flat zero of both copies
    __syncthreads();
    unsigned* __restrict__ my = lacc[(tid >> 6) & 1];
    unsigned len = gcur[b * 16];                  // padded records, mult of 4
    len = len > (unsigned)CAP ? (unsigned)CAP : len;
    const unsigned h = (len >> 1) & ~3u;
    const unsigned lo4 = (half ? h : 0u) >> 2;
    const unsigned hi4 = (half ? len : h) >> 2;
    const uint4* __restrict__ p =
        reinterpret_cast<const uint4*>(arena + (size_t)b * CAP);
    for (unsigned i = lo4 + tid; i < hi4; i += 1024) {
        const uint4 v = p[i];
        // deg in bits [24,32), sum(q16) in [0,24); PADREC -> sink slot
        atomicAdd(&my[v.x >> 16], (v.x & 0xFFFFu) | 0x1000000u);
        atomicAdd(&my[v.y >> 16], (v.y & 0xFFFFu) | 0x1000000u);
        atomicAdd(&my[v.z >> 16], (v.z & 0xFFFFu) | 0x1000000u);
        atomicAdd(&my[v.w >> 16], (v.w & 0xFFFFu) | 0x1000000u);
    }
    __syncthreads();
    const int base = b << BSHIFT;
    unsigned* __restrict__ dst = acc + (size_t)half * kNodes;
    for (int k = tid; k < BNODES; k += 1024) {
        const int nn = base + k;
        if (nn < kNodes) dst[nn] = lacc[0][k] + lacc[1][k];
    }
}

// Exact fixup for the (statistically ~0.1 expected) slab-overflow records.
__global__ __launch_bounds__(256) void ovf_fix(
        const unsigned long long* __restrict__ ovf,
        const unsigned* __restrict__ gcur, unsigned* __restrict__ acc) {
    unsigned n = gcur[NB * 16];
    n = n > OVFCAP ? OVFCAP : n;
    for (unsigned i = threadIdx.x; i < n; i += 256) {
        const unsigned long long v = ovf[i];
        atomicAdd(&acc[(unsigned)(v >> 16)],
                  ((unsigned)v & 0xFFFFu) | 0x1000000u);
    }
}

// ---------------- Fallback (atomic) path ----------------
constexpr float kScale = 1048576.0f;           // 2^20
constexpr float kInvScale = 1.0f / 1048576.0f;
constexpr long long kBias = 1ll << 36;

__global__ __launch_bounds__(256) void zero_acc(unsigned long long* __restrict__ acc) {
    int i = blockIdx.x * 256 + threadIdx.x;
    if (i < kNodes) acc[i] = 0ull;
}

__global__ __launch_bounds__(256) void edge_kernel(
        const int* __restrict__ ei,
        const float* __restrict__ orc,
        unsigned long long* __restrict__ acc) {
    int t = blockIdx.x * 256 + threadIdx.x;
    int e0 = t * 4;
    if (e0 >= kEdges) return;
    const int4 s4 = *reinterpret_cast<const int4*>(ei + e0);
    const int4 d4 = *reinterpret_cast<const int4*>(ei + kEdges + e0);
    const int ss[4] = {s4.x, s4.y, s4.z, s4.w};
    const int dd[4] = {d4.x, d4.y, d4.z, d4.w};
    #pragma unroll
    for (int k = 0; k < 4; ++k) {
        const float os = orc[ss[k]];
        const float od = orc[dd[k]];
        const unsigned long long ps =
            (1ull << 48) + (unsigned long long)(kBias + (long long)__float2ll_rn(od * kScale));
        const unsigned long long pd =
            (1ull << 48) + (unsigned long long)(kBias + (long long)__float2ll_rn(os * kScale));
        atomicAdd(&acc[ss[k]], ps);
        atomicAdd(&acc[dd[k]], pd);
    }
}

// ---------------- Node phase ----------------
// MODE 0: deg<<48 | biased 2^20 fixed sum (u64).
// MODE 3: two u32 partials, each deg<<24 | sum(q16).
template <int MODE>
__global__ __launch_bounds__(256) void node_kernel(
        const float* __restrict__ orc,
        const unsigned long long* __restrict__ acc64,
        const unsigned* __restrict__ acc32,
        const float* __restrict__ W1, const float* __restrict__ b1,
        const float* __restrict__ W2, const float* __restrict__ b2,
        const float* __restrict__ gamma, const float* __restrict__ beta,
        float* __restrict__ out) {
    const int i = blockIdx.x * 256 + threadIdx.x;
    if (i >= kNodes) return;

    const float x0 = orc[i];
    float nb;
    if (MODE == 0) {
        const unsigned long long p = acc64[i];
        const unsigned deg = (unsigned)(p >> 48);
        const long long sf = (long long)(p & ((1ull << 48) - 1)) - (long long)deg * kBias;
        const float s = (float)sf * kInvScale;
        nb = (deg > 0) ? s / (float)deg : 0.0f;
    } else {
        const unsigned p0 = acc32[i];
        const unsigned p1 = acc32[kNodes + i];
        const unsigned deg = (p0 >> 24) + (p1 >> 24);
        const unsigned sumq = (p0 & 0xFFFFFFu) + (p1 & 0xFFFFFFu);
        nb = (deg > 0)
            ? ((float)sumq * (1.0f / 32768.0f) / (float)deg - 1.0f) : 0.0f;
    }

    constexpr float kPi = 3.14159265358979323846f;
    float Phi[16];
    const float n0 = __saturatef((x0 + 1.0f) * 0.5f);
    const float n1 = __saturatef((nb + 1.0f) * 0.5f);
    #pragma unroll
    for (int k = 0; k < 4; ++k) {
        const float a0 = n0 * (float)(k + 1) * kPi;
        const float a1 = n1 * (float)(k + 1) * kPi;
        Phi[2 * k]     = __sinf(a0);
        Phi[2 * k + 1] = __cosf(a0);
        Phi[8 + 2 * k]     = __sinf(a1);
        Phi[8 + 2 * k + 1] = __cosf(a1);
    }

    float y[16];
    #pragma unroll
    for (int d = 0; d < 16; ++d) y[d] = b2[d];
    #pragma unroll
    for (int j = 0; j < 32; ++j) {
        float a = b1[j];
        #pragma unroll
        for (int d = 0; d < 16; ++d) a = fmaf(Phi[d], W1[j * 16 + d], a);
        a = fmaxf(a, 0.0f);
        #pragma unroll
        for (int d = 0; d < 16; ++d) y[d] = fmaf(a, W2[d * 32 + j], y[d]);
    }

    float mu = 0.0f;
    #pragma unroll
    for (int d = 0; d < 16; ++d) mu += y[d];
    mu *= (1.0f / 16.0f);
    float var = 0.0f;
    #pragma unroll
    for (int d = 0; d < 16; ++d) { const float t = y[d] - mu; var = fmaf(t, t, var); }
    var *= (1.0f / 16.0f);
    const float inv = rsqrtf(var + 1e-5f);

    float4* o4 = reinterpret_cast<float4*>(out + (size_t)i * 16);
    #pragma unroll
    for (int q = 0; q < 4; ++q) {
        float4 o;
        o.x = (y[4 * q + 0] - mu) * inv * gamma[4 * q + 0] + beta[4 * q + 0] + Phi[4 * q + 0];
        o.y = (y[4 * q + 1] - mu) * inv * gamma[4 * q + 1] + beta[4 * q + 1] + Phi[4 * q + 1];
        o.z = (y[4 * q + 2] - mu) * inv * gamma[4 * q + 2] + beta[4 * q + 2] + Phi[4 * q + 2];
        o.w = (y[4 * q + 3] - mu) * inv * gamma[4 * q + 3] + beta[4 * q + 3] + Phi[4 * q + 3];
        o4[q] = o;
    }
}

extern "C" void kernel_launch(void* const* d_in, const int* in_sizes, int n_in,
                              void* d_out, int out_size, void* d_ws, size_t ws_size,
                              hipStream_t stream) {
    const float* orc   = (const float*)d_in[0];
    const int*   ei    = (const int*)d_in[1];
    const float* W1    = (const float*)d_in[2];
    const float* b1    = (const float*)d_in[3];
    const float* W2    = (const float*)d_in[4];
    const float* b2    = (const float*)d_in[5];
    const float* gamma = (const float*)d_in[6];
    const float* beta  = (const float*)d_in[7];
    float* out = (float*)d_out;
    char* ws = (char*)d_ws;

    if (ws_size >= kWsNeeded) {
        unsigned* arena = (unsigned*)ws;
        unsigned* gcur = (unsigned*)(ws + kCurOff);
        unsigned* acc = (unsigned*)(ws + kAccOff);
        unsigned short* orcq = (unsigned short*)(ws + kOrcqOff);
        unsigned long long* ovf = (unsigned long long*)(ws + kOvfOff);
        quant_orc<<<(kNodes / 4 + 255) / 256, 256, 0, stream>>>(orc, orcq, gcur);
        scatter_sort<<<TILES, 1024, 0, stream>>>(ei, orcq, arena, gcur, ovf);
        bucket_accum<<<NBUSED * SPLIT, 1024, 0, stream>>>(arena, gcur, acc);
        ovf_fix<<<1, 256, 0, stream>>>(ovf, gcur, acc);
        node_kernel<3><<<(kNodes + 255) / 256, 256, 0, stream>>>(
            orc, nullptr, acc, W1, b1, W2, b2, gamma, beta, out);
    } else {
        unsigned long long* acc = (unsigned long long*)ws;  // 8 MB
        zero_acc<<<(kNodes + 255) / 256, 256, 0, stream>>>(acc);
        edge_kernel<<<(kEdges / 4 + 255) / 256, 256, 0, stream>>>(ei, orc, acc);
        node_kernel<0><<<(kNodes + 255) / 256, 256, 0, stream>>>(
            orc, acc, nullptr, W1, b1, W2, b2, gamma, beta, out);
    }
}